// Round 4
// baseline (522.503 us; speedup 1.0000x reference)
//
#include <hip/hip_runtime.h>
#include <hip/hip_bf16.h>

typedef __bf16 bf16_t;
typedef __bf16 bf16x8 __attribute__((ext_vector_type(8)));
typedef __bf16 bf16x4v __attribute__((ext_vector_type(4)));
typedef float f32x4 __attribute__((ext_vector_type(4)));
typedef float f32x16 __attribute__((ext_vector_type(16)));

#define HIDDEN 3584
#define SEQ 2048
#define NHEADS 28
#define NKV 4
#define HDIM 128
#define GROUPS 7
#define QKV_LD 4608
#define SCL_LOG2 (0.08838834764831845f * 1.44269504088896f)

__device__ inline f32x4 mfma16(bf16x8 a, bf16x8 b, f32x4 c) {
    return __builtin_amdgcn_mfma_f32_16x16x32_bf16(a, b, c, 0, 0, 0);
}

__device__ inline f32x16 mfma32(bf16x8 a, bf16x8 b, f32x16 c) {
    return __builtin_amdgcn_mfma_f32_32x32x16_bf16(a, b, c, 0, 0, 0);
}

__device__ inline void gl_lds16(const bf16_t* g, bf16_t* l) {
    __builtin_amdgcn_global_load_lds(
        (const __attribute__((address_space(1))) void*)g,
        (__attribute__((address_space(3))) void*)l, 16, 0, 0);
}

// ---------------- fused fp32 -> bf16 convert (all 5 tensors, 1 dispatch) ----------------
#define HS_F4   1835008   // 2048*3584/4
#define WQ_F4   3211264   // 3584*3584/4
#define WK_F4    458752   // 512*3584/4
#define WV_F4    458752
#define WO_F4   3211264
__global__ void cvt_all_kernel(const float* __restrict__ hs, const float* __restrict__ Wq,
                               const float* __restrict__ Wk, const float* __restrict__ Wv,
                               const float* __restrict__ Wo,
                               bf16_t* __restrict__ hsb, bf16_t* __restrict__ Wqkvb,
                               bf16_t* __restrict__ Wob) {
    int i = blockIdx.x * 256 + threadIdx.x;
    const float* s; bf16_t* d; int off;
    if (i < HS_F4) { s = hs; d = hsb; off = i; }
    else if (i < HS_F4 + WQ_F4) { s = Wq; d = Wqkvb; off = i - HS_F4; }
    else if (i < HS_F4 + WQ_F4 + WK_F4) { s = Wk; d = Wqkvb + 4 * (size_t)WQ_F4; off = i - HS_F4 - WQ_F4; }
    else if (i < HS_F4 + WQ_F4 + WK_F4 + WV_F4) { s = Wv; d = Wqkvb + 4 * ((size_t)WQ_F4 + WK_F4); off = i - HS_F4 - WQ_F4 - WK_F4; }
    else { s = Wo; d = Wob; off = i - HS_F4 - WQ_F4 - WK_F4 - WV_F4; }
    float4 f = ((const float4*)s)[off];
    bf16x4v o;
    o.x = (bf16_t)f.x; o.y = (bf16_t)f.y; o.z = (bf16_t)f.z; o.w = (bf16_t)f.w;
    ((bf16x4v*)d)[off] = o;
}

// ---------------- bias concat (bq|bk|bv) ----------------
__global__ void bcat_kernel(const float* __restrict__ bq, const float* __restrict__ bk,
                            const float* __restrict__ bv, float* __restrict__ dst) {
    int i = blockIdx.x * 256 + threadIdx.x;
    if (i < QKV_LD) {
        float v = (i < HIDDEN) ? bq[i] : (i < HIDDEN + 512 ? bk[i - HIDDEN] : bv[i - HIDDEN - 512]);
        dst[i] = v;
    }
}

// ---------------- GEMM: C[M,N] = A[M,K] @ B[N,K]^T (+bias) ----------------
// 128x128 tile, BK=64 staged as 2 x 32-col panels (m97 geometry per panel).
template <bool OUT_BF16>
__global__ __launch_bounds__(256) void gemm_bt(
    const bf16_t* __restrict__ A, const bf16_t* __restrict__ B,
    const float* __restrict__ bias, void* __restrict__ Cout,
    int M, int N, int K) {
    __shared__ __align__(16) bf16_t As[2][128 * 32];
    __shared__ __align__(16) bf16_t Bs[2][128 * 32];
    const int tid = threadIdx.x;
    const int w = tid >> 6, lane = tid & 63;
    const int quad = lane >> 4, l16 = lane & 15;
    const int wm = w >> 1, wn = w & 1;
    const int m0 = blockIdx.y * 128, n0 = blockIdx.x * 128;
    f32x4 acc[4][4] = {};
    for (int k0 = 0; k0 < K; k0 += 64) {
        __syncthreads();
#pragma unroll
        for (int p = 0; p < 2; ++p)
#pragma unroll
            for (int i = 0; i < 2; ++i) {
                int ca = (w * 2 + i) * 64 + lane;          // chunk 0..511 within panel
                int row = ca >> 2, kc = ca & 3;
                gl_lds16(A + (size_t)(m0 + row) * K + k0 + p * 32 + kc * 8,
                         As[p] + (size_t)(w * 2 + i) * 512);
                gl_lds16(B + (size_t)(n0 + row) * K + k0 + p * 32 + kc * 8,
                         Bs[p] + (size_t)(w * 2 + i) * 512);
            }
        __syncthreads();
#pragma unroll
        for (int p = 0; p < 2; ++p) {
            bf16x8 a[4], b[4];
#pragma unroll
            for (int i = 0; i < 4; ++i)
                a[i] = *(const bf16x8*)(As[p] + (wm * 64 + i * 16 + l16) * 32 + quad * 8);
#pragma unroll
            for (int j = 0; j < 4; ++j)
                b[j] = *(const bf16x8*)(Bs[p] + (wn * 64 + j * 16 + l16) * 32 + quad * 8);
#pragma unroll
            for (int i = 0; i < 4; ++i)
#pragma unroll
                for (int j = 0; j < 4; ++j)
                    acc[i][j] = mfma16(a[i], b[j], acc[i][j]);
        }
    }
#pragma unroll
    for (int i = 0; i < 4; ++i) {
#pragma unroll
        for (int j = 0; j < 4; ++j) {
            int col = n0 + wn * 64 + j * 16 + l16;
            float bv_ = bias ? bias[col] : 0.f;
#pragma unroll
            for (int r = 0; r < 4; ++r) {
                int row = m0 + wm * 64 + i * 16 + quad * 4 + r;
                float v = acc[i][j][r] + bv_;
                if (OUT_BF16) ((bf16_t*)Cout)[(size_t)row * N + col] = (bf16_t)v;
                else          ((float*)Cout)[(size_t)row * N + col] = v;
            }
        }
    }
}

// ---------------- RoPE (in-place on bf16 qkv buffer) ----------------
__global__ void rope_kernel(bf16_t* __restrict__ qkv,
                            const float* __restrict__ cosb, const float* __restrict__ sinb) {
    int t = blockIdx.x * 256 + threadIdx.x;   // SEQ * 32 * 64 total
    int d = t & 63;
    int hh = (t >> 6) & 31;
    int s = t >> 11;
    float c0 = cosb[s * 128 + d], sn0 = sinb[s * 128 + d];
    float c1 = cosb[s * 128 + d + 64], sn1 = sinb[s * 128 + d + 64];
    bf16_t* p;
    if (hh < NHEADS) p = qkv + (size_t)s * QKV_LD + hh * HDIM;
    else             p = qkv + (size_t)s * QKV_LD + HIDDEN + (hh - NHEADS) * HDIM;
    float x0 = (float)p[d], x1 = (float)p[d + 64];
    p[d]      = (bf16_t)(x0 * c0 - x1 * sn0);
    p[d + 64] = (bf16_t)(x1 * c1 + x0 * sn1);
}

// ---------------- Flash attention v5: mfma32 32q/wave + kv-parity split for long tiles ----------
// q-tiles: 64 rows, qb in 0..31. Blocks: 256 threads = 4 waves = 2 groups x (2 waves x 32q).
// grid (24, NHEADS):
//   bx 0..7  : unsplit pair, group0 qb=15-bx (long), group1 qb=bx; kv tiles 0..qb step 1
//   bx 8..23 : split; idx=bx-8, h=idx>>3, j=idx&7; group0 qb=31-j, group1 qb=16+j;
//              kv tiles h, h+2, ... (parity h). Partials (m,l,o-unnormalized f32) -> combine.
// LDS swizzles + fragment maps identical to the R2-verified kernel:
//  Ks [64][128] linear, 16B-chunk swizzle col16 ^= (row&7); Vt [128][64] V^T, 8B-chunk col8 ^= (d&7)
//  slot map: kv = 16*m + 8*(e>=4) + 4*hf + (e&3); C layout col=lane&31, row=(reg&3)+8*(reg>>2)+4*(lane>>5)
__global__ __launch_bounds__(256) void attn_kernel(
    const bf16_t* __restrict__ qkv, bf16_t* __restrict__ o_out,
    float* __restrict__ opart, float* __restrict__ mlpart) {
    __shared__ __align__(16) bf16_t Ks[64 * 128];
    __shared__ __align__(16) bf16_t Vt[128 * 64];
    const int tid = threadIdx.x;
    const int w = tid >> 6, lane = tid & 63;
    const int quad = lane >> 4, l16 = lane & 15;
    const int l31 = lane & 31, hf = lane >> 5;
    const int head = blockIdx.y, kvh = head / GROUPS;
    const int bx = blockIdx.x;

    int qb0, qb1, kbase, kstep; bool split;
    if (bx < 8) { split = false; kbase = 0; kstep = 1; qb0 = 15 - bx; qb1 = bx; }
    else { split = true; int idx = bx - 8; kbase = idx >> 3; kstep = 2;
           int j = idx & 7; qb0 = 31 - j; qb1 = 16 + j; }

    const int grp = w >> 1, wq = w & 1;
    const int qb = grp ? qb1 : qb0;
    const int n_me = split ? ((qb - kbase) >> 1) + 1 : qb + 1;
    const int ntk  = split ? ((qb0 - kbase) >> 1) + 1 : qb0 + 1;   // group0 is the long one

    const bf16_t* qp = qkv + head * HDIM;
    const bf16_t* kp = qkv + HIDDEN + kvh * HDIM;
    const bf16_t* vp = qkv + HIDDEN + 512 + kvh * HDIM;
    const int rowq = qb * 64 + wq * 32 + l31;

    // Q row in registers: qa[kc][e] = Q[rowq][kc*16 + 8*hf + e]
    bf16x8 qa[8];
#pragma unroll
    for (int kc = 0; kc < 8; ++kc)
        qa[kc] = *(const bf16x8*)(qp + (size_t)rowq * QKV_LD + kc * 16 + hf * 8);

    f32x16 o[4] = {};
    float m_r = -1.0e30f, l_r = 0.f;

    int4 kr[4], vr[4];
    auto loadT = [&](int kv0) {
#pragma unroll
        for (int i = 0; i < 4; ++i)
            kr[i] = *(const int4*)(kp + (size_t)(kv0 + w * 4 + 16 * i + quad) * QKV_LD + l16 * 8);
#pragma unroll
        for (int i = 0; i < 4; ++i)
            vr[i] = *(const int4*)(vp + (size_t)(kv0 + lane) * QKV_LD + (w + 4 * i) * 8);
    };
    loadT(kbase * 64);

    for (int it = 0; it < ntk; ++it) {
        const int kv0 = (kbase + kstep * it) * 64;
        __syncthreads();
        // ---- stage K (vector, swizzled) ----
#pragma unroll
        for (int i = 0; i < 4; ++i) {
            int r = w * 4 + 16 * i + quad;
            *(int4*)&Ks[r * 128 + 8 * (l16 ^ (r & 7))] = kr[i];
        }
        // ---- stage V^T (scalar, swizzled) ----
#pragma unroll
        for (int i = 0; i < 4; ++i) {
            bf16_t* ts = (bf16_t*)&vr[i];
#pragma unroll
            for (int i2 = 0; i2 < 8; ++i2) {
                int d = (w + 4 * i) * 8 + i2;
                Vt[d * 64 + 4 * ((lane >> 2) ^ (d & 7)) + (lane & 3)] = ts[i2];
            }
        }
        __syncthreads();
        if (it + 1 < ntk) loadT((kbase + kstep * (it + 1)) * 64);   // prefetch overlaps compute

        if (it < n_me) {
            // ---- QK^T: S^T[kv][q], two 32-kv subtiles ----
            f32x16 s0 = {}, s1 = {};
            const int kkey = l31 & 7;
#pragma unroll
            for (int kc = 0; kc < 8; ++kc) {
                int csw = 8 * ((2 * kc + hf) ^ kkey);
                bf16x8 kb0 = *(const bf16x8*)&Ks[l31 * 128 + csw];
                bf16x8 kb1 = *(const bf16x8*)&Ks[(32 + l31) * 128 + csw];
                s0 = mfma32(kb0, qa[kc], s0);
                s1 = mfma32(kb1, qa[kc], s1);
            }
            // ---- online softmax ----
            float mx = -1.0e30f;
#pragma unroll
            for (int j = 0; j < 16; ++j) {
                int kvg = kv0 + (j & 3) + 8 * (j >> 2) + 4 * hf;
                float x0 = s0[j] * SCL_LOG2; if (kvg > rowq) x0 = -1.0e30f; s0[j] = x0;
                float x1 = s1[j] * SCL_LOG2; if (kvg + 32 > rowq) x1 = -1.0e30f; s1[j] = x1;
                mx = fmaxf(mx, fmaxf(x0, x1));
            }
            mx = fmaxf(mx, __shfl_xor(mx, 32));
            float mn = fmaxf(m_r, mx);
            float al = __builtin_amdgcn_exp2f(m_r - mn);
            m_r = mn;
            float rs = 0.f;
#pragma unroll
            for (int j = 0; j < 16; ++j) {
                float p0 = __builtin_amdgcn_exp2f(s0[j] - mn); s0[j] = p0;
                float p1 = __builtin_amdgcn_exp2f(s1[j] - mn); s1[j] = p1;
                rs += p0 + p1;
            }
            rs += __shfl_xor(rs, 32);
            l_r = al * l_r + rs;
#pragma unroll
            for (int dt = 0; dt < 4; ++dt)
#pragma unroll
                for (int j = 0; j < 16; ++j) o[dt][j] *= al;

            // ---- pack P -> bf16; pb[m] slot e holds kv = 16m + 8*(e>=4) + 4hf + (e&3) ----
            bf16x8 pb[4];
#pragma unroll
            for (int m = 0; m < 4; ++m)
#pragma unroll
                for (int jj = 0; jj < 8; ++jj)
                    pb[m][jj] = (bf16_t)((m < 2 ? s0 : s1)[8 * (m & 1) + jj]);

            // ---- PV: O^T[d][q] ----
#pragma unroll
            for (int dt = 0; dt < 4; ++dt) {
                const int dr = dt * 32 + l31;
                const int vkey = dr & 7;
                const bf16_t* vb = &Vt[dr * 64];
#pragma unroll
                for (int m = 0; m < 4; ++m) {
                    bf16x4v lo = *(const bf16x4v*)&vb[4 * ((4 * m + hf) ^ vkey)];
                    bf16x4v hi = *(const bf16x4v*)&vb[4 * ((4 * m + 2 + hf) ^ vkey)];
                    bf16x8 va = __builtin_shufflevector(lo, hi, 0, 1, 2, 3, 4, 5, 6, 7);
                    o[dt] = mfma32(va, pb[m], o[dt]);
                }
            }
        }
    }

    if (!split) {
        float inv_l = 1.0f / l_r;
#pragma unroll
        for (int dt = 0; dt < 4; ++dt)
#pragma unroll
            for (int d3 = 0; d3 < 4; ++d3) {
                bf16x4v ov;
#pragma unroll
                for (int c = 0; c < 4; ++c) ov[c] = (bf16_t)(o[dt][4 * d3 + c] * inv_l);
                *(bf16x4v*)&o_out[(size_t)rowq * HIDDEN + head * HDIM + dt * 32 + d3 * 8 + 4 * hf] = ov;
            }
    } else {
        // store unnormalized f32 partials + (m,l)
        const int prow = (head * 1024 + (rowq - 1024)) * 2 + kbase;
        float* op = opart + (size_t)prow * 128;
#pragma unroll
        for (int dt = 0; dt < 4; ++dt)
#pragma unroll
            for (int d3 = 0; d3 < 4; ++d3) {
                f32x4 ov;
#pragma unroll
                for (int c = 0; c < 4; ++c) ov[c] = o[dt][4 * d3 + c];
                *(f32x4*)&op[dt * 32 + d3 * 8 + 4 * hf] = ov;
            }
        if (hf == 0) {
            mlpart[prow * 2]     = m_r;
            mlpart[prow * 2 + 1] = l_r;
        }
    }
}

// ---------------- combine the two kv-parity partials for q rows 1024..2047 ----------------
__global__ void combine_kernel(const float* __restrict__ opart, const float* __restrict__ mlpart,
                               bf16_t* __restrict__ o_out) {
    int t = blockIdx.x * 256 + threadIdx.x;   // 28*1024*32 = 917504
    int d4 = t & 31;
    int row = (t >> 5) & 1023;
    int head = t >> 15;
    int base = (head * 1024 + row) * 2;
    float m0 = mlpart[base * 2],     l0 = mlpart[base * 2 + 1];
    float m1 = mlpart[base * 2 + 2], l1 = mlpart[base * 2 + 3];
    float m = fmaxf(m0, m1);
    float a0 = __builtin_amdgcn_exp2f(m0 - m);
    float a1 = __builtin_amdgcn_exp2f(m1 - m);
    float inv = 1.0f / (l0 * a0 + l1 * a1);
    f32x4 o0 = *(const f32x4*)&opart[(size_t)base * 128 + d4 * 4];
    f32x4 o1 = *(const f32x4*)&opart[(size_t)(base + 1) * 128 + d4 * 4];
    bf16x4v ov;
#pragma unroll
    for (int c = 0; c < 4; ++c) ov[c] = (bf16_t)((o0[c] * a0 + o1[c] * a1) * inv);
    *(bf16x4v*)&o_out[(size_t)(1024 + row) * HIDDEN + head * HDIM + d4 * 4] = ov;
}

extern "C" void kernel_launch(void* const* d_in, const int* in_sizes, int n_in,
                              void* d_out, int out_size, void* d_ws, size_t ws_size,
                              hipStream_t stream) {
    const float* hs   = (const float*)d_in[0];
    const float* cosb = (const float*)d_in[1];
    const float* sinb = (const float*)d_in[2];
    const float* Wq   = (const float*)d_in[3];
    const float* bq   = (const float*)d_in[4];
    const float* Wk   = (const float*)d_in[5];
    const float* bk   = (const float*)d_in[6];
    const float* Wv   = (const float*)d_in[7];
    const float* bv   = (const float*)d_in[8];
    const float* Wo   = (const float*)d_in[9];
    float* out = (float*)d_out;

    char* p = (char*)d_ws;
    bf16_t* hsb   = (bf16_t*)p; p += (size_t)SEQ * HIDDEN * 2;        // also reused as attn out
    bf16_t* Wqkvb = (bf16_t*)p; p += (size_t)QKV_LD * HIDDEN * 2;
    bf16_t* Wob   = (bf16_t*)p; p += (size_t)HIDDEN * HIDDEN * 2;
    bf16_t* qkvb  = (bf16_t*)p; p += (size_t)SEQ * QKV_LD * 2;
    float*  bcat  = (float*)p;  p += (size_t)QKV_LD * 4;

    // attn partials overlay the Wqkvb region (dead after gemm1):
    // opart: 28*1024*2*128 f32 = 29.36 MB, mlpart: 28*1024*2*2 f32 = 0.46 MB  (< 33.03 MB)
    float* opart  = (float*)Wqkvb;
    float* mlpart = opart + (size_t)NHEADS * 1024 * 2 * 128;

    const int total_f4 = HS_F4 + WQ_F4 + WK_F4 + WV_F4 + WO_F4;
    cvt_all_kernel<<<(total_f4 + 255) / 256, 256, 0, stream>>>(
        hs, Wq, Wk, Wv, Wo, hsb, Wqkvb, Wob);
    bcat_kernel<<<(QKV_LD + 255) / 256, 256, 0, stream>>>(bq, bk, bv, bcat);

    gemm_bt<true><<<dim3(QKV_LD / 128, SEQ / 128), 256, 0, stream>>>(
        hsb, Wqkvb, bcat, qkvb, SEQ, QKV_LD, HIDDEN);

    rope_kernel<<<(SEQ * 32 * 64) / 256, 256, 0, stream>>>(qkvb, cosb, sinb);

    attn_kernel<<<dim3(24, NHEADS), 256, 0, stream>>>(qkvb, hsb, opart, mlpart);
    combine_kernel<<<NHEADS * 1024 * 32 / 256, 256, 0, stream>>>(opart, mlpart, hsb);

    gemm_bt<false><<<dim3(HIDDEN / 128, SEQ / 128), 256, 0, stream>>>(
        hsb, Wob, nullptr, out, SEQ, HIDDEN, HIDDEN);
}

// Round 5
// 475.926 us; speedup vs baseline: 1.0979x; 1.0979x over previous
//
#include <hip/hip_runtime.h>
#include <hip/hip_bf16.h>

typedef __bf16 bf16_t;
typedef __bf16 bf16x8 __attribute__((ext_vector_type(8)));
typedef __bf16 bf16x4v __attribute__((ext_vector_type(4)));
typedef float f32x4 __attribute__((ext_vector_type(4)));

#define HIDDEN 3584
#define SEQ 2048
#define NHEADS 28
#define NKV 4
#define HDIM 128
#define GROUPS 7
#define QKV_LD 4608
#define SCL_LOG2 (0.08838834764831845f * 1.44269504088896f)

__device__ inline f32x4 mfma16(bf16x8 a, bf16x8 b, f32x4 c) {
    return __builtin_amdgcn_mfma_f32_16x16x32_bf16(a, b, c, 0, 0, 0);
}

__device__ inline void gl_lds16(const bf16_t* g, bf16_t* l) {
    __builtin_amdgcn_global_load_lds(
        (const __attribute__((address_space(1))) void*)g,
        (__attribute__((address_space(3))) void*)l, 16, 0, 0);
}

// ---------------- fused fp32 -> bf16 convert (all 5 tensors, 1 dispatch) ----------------
#define HS_F4   1835008   // 2048*3584/4
#define WQ_F4   3211264   // 3584*3584/4
#define WK_F4    458752   // 512*3584/4
#define WV_F4    458752
#define WO_F4   3211264
__global__ void cvt_all_kernel(const float* __restrict__ hs, const float* __restrict__ Wq,
                               const float* __restrict__ Wk, const float* __restrict__ Wv,
                               const float* __restrict__ Wo,
                               bf16_t* __restrict__ hsb, bf16_t* __restrict__ Wqkvb,
                               bf16_t* __restrict__ Wob) {
    int i = blockIdx.x * 256 + threadIdx.x;
    const float* s; bf16_t* d; int off;
    if (i < HS_F4) { s = hs; d = hsb; off = i; }
    else if (i < HS_F4 + WQ_F4) { s = Wq; d = Wqkvb; off = i - HS_F4; }
    else if (i < HS_F4 + WQ_F4 + WK_F4) { s = Wk; d = Wqkvb + 4 * (size_t)WQ_F4; off = i - HS_F4 - WQ_F4; }
    else if (i < HS_F4 + WQ_F4 + WK_F4 + WV_F4) { s = Wv; d = Wqkvb + 4 * ((size_t)WQ_F4 + WK_F4); off = i - HS_F4 - WQ_F4 - WK_F4; }
    else { s = Wo; d = Wob; off = i - HS_F4 - WQ_F4 - WK_F4 - WV_F4; }
    float4 f = ((const float4*)s)[off];
    bf16x4v o;
    o.x = (bf16_t)f.x; o.y = (bf16_t)f.y; o.z = (bf16_t)f.z; o.w = (bf16_t)f.w;
    ((bf16x4v*)d)[off] = o;
}

// ---------------- bias concat (bq|bk|bv) ----------------
__global__ void bcat_kernel(const float* __restrict__ bq, const float* __restrict__ bk,
                            const float* __restrict__ bv, float* __restrict__ dst) {
    int i = blockIdx.x * 256 + threadIdx.x;
    if (i < QKV_LD) {
        float v = (i < HIDDEN) ? bq[i] : (i < HIDDEN + 512 ? bk[i - HIDDEN] : bv[i - HIDDEN - 512]);
        dst[i] = v;
    }
}

// ---------------- GEMM: C[M,N] = A[M,K] @ B[N,K]^T (+bias) ----------------
// 128x128 tile, BK=64 staged as 2 x 32-col panels (m97 geometry per panel).
template <bool OUT_BF16>
__global__ __launch_bounds__(256) void gemm_bt(
    const bf16_t* __restrict__ A, const bf16_t* __restrict__ B,
    const float* __restrict__ bias, void* __restrict__ Cout,
    int M, int N, int K) {
    __shared__ __align__(16) bf16_t As[2][128 * 32];
    __shared__ __align__(16) bf16_t Bs[2][128 * 32];
    const int tid = threadIdx.x;
    const int w = tid >> 6, lane = tid & 63;
    const int quad = lane >> 4, l16 = lane & 15;
    const int wm = w >> 1, wn = w & 1;
    const int m0 = blockIdx.y * 128, n0 = blockIdx.x * 128;
    f32x4 acc[4][4] = {};
    for (int k0 = 0; k0 < K; k0 += 64) {
        __syncthreads();
#pragma unroll
        for (int p = 0; p < 2; ++p)
#pragma unroll
            for (int i = 0; i < 2; ++i) {
                int ca = (w * 2 + i) * 64 + lane;          // chunk 0..511 within panel
                int row = ca >> 2, kc = ca & 3;
                gl_lds16(A + (size_t)(m0 + row) * K + k0 + p * 32 + kc * 8,
                         As[p] + (size_t)(w * 2 + i) * 512);
                gl_lds16(B + (size_t)(n0 + row) * K + k0 + p * 32 + kc * 8,
                         Bs[p] + (size_t)(w * 2 + i) * 512);
            }
        __syncthreads();
#pragma unroll
        for (int p = 0; p < 2; ++p) {
            bf16x8 a[4], b[4];
#pragma unroll
            for (int i = 0; i < 4; ++i)
                a[i] = *(const bf16x8*)(As[p] + (wm * 64 + i * 16 + l16) * 32 + quad * 8);
#pragma unroll
            for (int j = 0; j < 4; ++j)
                b[j] = *(const bf16x8*)(Bs[p] + (wn * 64 + j * 16 + l16) * 32 + quad * 8);
#pragma unroll
            for (int i = 0; i < 4; ++i)
#pragma unroll
                for (int j = 0; j < 4; ++j)
                    acc[i][j] = mfma16(a[i], b[j], acc[i][j]);
        }
    }
#pragma unroll
    for (int i = 0; i < 4; ++i) {
#pragma unroll
        for (int j = 0; j < 4; ++j) {
            int col = n0 + wn * 64 + j * 16 + l16;
            float bv_ = bias ? bias[col] : 0.f;
#pragma unroll
            for (int r = 0; r < 4; ++r) {
                int row = m0 + wm * 64 + i * 16 + quad * 4 + r;
                float v = acc[i][j][r] + bv_;
                if (OUT_BF16) ((bf16_t*)Cout)[(size_t)row * N + col] = (bf16_t)v;
                else          ((float*)Cout)[(size_t)row * N + col] = v;
            }
        }
    }
}

// ---------------- RoPE (in-place on bf16 qkv buffer) ----------------
__global__ void rope_kernel(bf16_t* __restrict__ qkv,
                            const float* __restrict__ cosb, const float* __restrict__ sinb) {
    int t = blockIdx.x * 256 + threadIdx.x;   // SEQ * 32 * 64 total
    int d = t & 63;
    int hh = (t >> 6) & 31;
    int s = t >> 11;
    float c0 = cosb[s * 128 + d], sn0 = sinb[s * 128 + d];
    float c1 = cosb[s * 128 + d + 64], sn1 = sinb[s * 128 + d + 64];
    bf16_t* p;
    if (hh < NHEADS) p = qkv + (size_t)s * QKV_LD + hh * HDIM;
    else             p = qkv + (size_t)s * QKV_LD + HIDDEN + (hh - NHEADS) * HDIM;
    float x0 = (float)p[d], x1 = (float)p[d + 64];
    p[d]      = (bf16_t)(x0 * c0 - x1 * sn0);
    p[d + 64] = (bf16_t)(x1 * c1 + x0 * sn1);
}

// ---------------- Flash attention (R3 inner loop + kv-parity split for long q-tiles) ----------
// 512 threads = 8 waves = 2 groups x 4 waves; groups share K/V staging.
// grid (24, NHEADS):
//   bx 0..7  : unsplit; group0 qb=15-bx, group1 qb=bx; kv tiles 0..qb step 1 -> bf16 out
//   bx 8..23 : split; idx=bx-8, parity=idx>>3, j=idx&7; group0 qb=31-j, group1 qb=16+j;
//              kv tiles parity, parity+2, ... -> f32 partials (m,l,unnormalized O) -> combine
// Inner loop, LDS layout (odd-dword strides), staging distribution: identical to R3.
// kv fragment-row permutation: F(st,m) = 32*(st>>1) + 8*(m>>2) + 4*(st&1) + (m&3)
__global__ __launch_bounds__(512, 4) void attn_kernel(
    const bf16_t* __restrict__ qkv, bf16_t* __restrict__ o_out,
    float* __restrict__ opart, float* __restrict__ mlpart) {
    __shared__ __align__(16) bf16_t Ks[64][130];   // kv x d, odd-dword row stride (65)
    __shared__ __align__(16) bf16_t Vt[128][66];   // d x kv, odd-dword row stride (33)
    const int tid = threadIdx.x;
    const int w = tid >> 6, lane = tid & 63;
    const int quad = lane >> 4, l16 = lane & 15;
    const int wq = w & 3;                 // wave index within its q-tile group
    const int grp = w >> 2;               // 0 = long tile, 1 = short tile
    const int h = blockIdx.y, kvh = h / GROUPS;
    const int bx = blockIdx.x;

    int qb0, qb1, kbase, kstep; bool split;
    if (bx < 8) { split = false; kbase = 0; kstep = 1; qb0 = 15 - bx; qb1 = bx; }
    else { split = true; int idx = bx - 8; kbase = idx >> 3; kstep = 2;
           int j = idx & 7; qb0 = 31 - j; qb1 = 16 + j; }

    const int qb   = grp ? qb1 : qb0;
    const int n_me = (qb  - kbase) / kstep + 1;   // this group's compute-tile count
    const int ntk  = (qb0 - kbase) / kstep + 1;   // staged tiles (group0 is the long one)

    const bf16_t* qp = qkv + h * HDIM;
    const bf16_t* kp = qkv + HIDDEN + kvh * HDIM;
    const bf16_t* vp = qkv + HIDDEN + 512 + kvh * HDIM;
    int frow[4];
#pragma unroll
    for (int st = 0; st < 4; ++st)
        frow[st] = 32 * (st >> 1) + 8 * (l16 >> 2) + 4 * (st & 1) + (l16 & 3);

    const int rowq = qb * 64 + wq * 16 + l16;   // this lane's q-row (as column of S^T)
    bf16x8 qa[4];
#pragma unroll
    for (int kc = 0; kc < 4; ++kc)
        qa[kc] = *(const bf16x8*)(qp + (size_t)rowq * QKV_LD + kc * 32 + quad * 8);
    f32x4 o[8] = {};
    float m_r = -1.0e30f, l_r = 0.f;

    int4 kr[2], vr[2];
    auto loadT = [&](int kv0) {
#pragma unroll
        for (int i = 0; i < 2; ++i)
            kr[i] = *(const int4*)(kp + (size_t)(kv0 + (w * 2 + i) * 4 + quad) * QKV_LD + l16 * 8);
#pragma unroll
        for (int i = 0; i < 2; ++i)
            vr[i] = *(const int4*)(vp + (size_t)(kv0 + lane) * QKV_LD + (w * 2 + i) * 8);
    };
    loadT(kbase * 64);

    for (int it = 0; it < ntk; ++it) {
        const int kv0 = (kbase + kstep * it) * 64;
        __syncthreads();
#pragma unroll
        for (int i = 0; i < 2; ++i)
            *(int4*)&Ks[(w * 2 + i) * 4 + quad][l16 * 8] = kr[i];
#pragma unroll
        for (int i = 0; i < 2; ++i) {
            bf16_t* ts = (bf16_t*)&vr[i];
#pragma unroll
            for (int i2 = 0; i2 < 8; ++i2) Vt[(w * 2 + i) * 8 + i2][lane] = ts[i2];
        }
        __syncthreads();
        if (it + 1 < ntk) loadT((kbase + kstep * (it + 1)) * 64);   // prefetch overlaps compute
        if (it < n_me) {
            f32x4 s[4] = {};
#pragma unroll
            for (int kc = 0; kc < 4; ++kc)
#pragma unroll
                for (int st = 0; st < 4; ++st) {
                    bf16x8 kb = *(const bf16x8*)&Ks[frow[st]][kc * 32 + quad * 8];
                    s[st] = mfma16(kb, qa[kc], s[st]);
                }
            const bool diag = ((kv0 >> 6) == qb);   // tile containing the causal diagonal
            float xv[4][4], mx = -1.0e30f;
#pragma unroll
            for (int st = 0; st < 4; ++st)
#pragma unroll
                for (int r = 0; r < 4; ++r) {
                    int kvg = kv0 + 32 * (st >> 1) + 8 * quad + 4 * (st & 1) + r;
                    float x = s[st][r] * SCL_LOG2;
                    if (diag && kvg > rowq) x = -1.0e30f;
                    xv[st][r] = x;
                    mx = fmaxf(mx, x);
                }
            mx = fmaxf(mx, __shfl_xor(mx, 16));
            mx = fmaxf(mx, __shfl_xor(mx, 32));
            float mn = fmaxf(m_r, mx);
            float al = __builtin_amdgcn_exp2f(m_r - mn);
            m_r = mn;
            float rs = 0.f;
            bf16x8 pb0, pb1;
#pragma unroll
            for (int r = 0; r < 4; ++r) {
                float p00 = __builtin_amdgcn_exp2f(xv[0][r] - mn);
                float p01 = __builtin_amdgcn_exp2f(xv[1][r] - mn);
                float p10 = __builtin_amdgcn_exp2f(xv[2][r] - mn);
                float p11 = __builtin_amdgcn_exp2f(xv[3][r] - mn);
                rs += (p00 + p01) + (p10 + p11);
                pb0[r] = (bf16_t)p00; pb0[4 + r] = (bf16_t)p01;
                pb1[r] = (bf16_t)p10; pb1[4 + r] = (bf16_t)p11;
            }
            rs += __shfl_xor(rs, 16);
            rs += __shfl_xor(rs, 32);
            l_r = al * l_r + rs;
#pragma unroll
            for (int dd = 0; dd < 8; ++dd) {
#pragma unroll
                for (int r = 0; r < 4; ++r) o[dd][r] *= al;
                bf16x8 va0 = *(const bf16x8*)&Vt[dd * 16 + l16][quad * 8];
                bf16x8 va1 = *(const bf16x8*)&Vt[dd * 16 + l16][32 + quad * 8];
                o[dd] = mfma16(va1, pb1, mfma16(va0, pb0, o[dd]));
            }
        }
    }
    if (!split) {
        float inv_l = 1.0f / l_r;
#pragma unroll
        for (int dd = 0; dd < 8; ++dd) {
            bf16x4v ov;
#pragma unroll
            for (int r = 0; r < 4; ++r) ov[r] = (bf16_t)(o[dd][r] * inv_l);
            *(bf16x4v*)&o_out[(size_t)rowq * HIDDEN + h * HDIM + dd * 16 + quad * 4] = ov;
        }
    } else {
        // unnormalized f32 partials; rows 1024..2047; parity = kbase
        const int prow = (h * 1024 + (rowq - 1024)) * 2 + kbase;
        float* op = opart + (size_t)prow * 128;
#pragma unroll
        for (int dd = 0; dd < 8; ++dd)
            *(f32x4*)&op[dd * 16 + quad * 4] = o[dd];
        if (quad == 0) {
            mlpart[prow * 2]     = m_r;
            mlpart[prow * 2 + 1] = l_r;
        }
    }
}

// ---------------- combine the two kv-parity partials for q rows 1024..2047 ----------------
__global__ void combine_kernel(const float* __restrict__ opart, const float* __restrict__ mlpart,
                               bf16_t* __restrict__ o_out) {
    int t = blockIdx.x * 256 + threadIdx.x;   // 28*1024*32 = 917504
    int d4 = t & 31;
    int row = (t >> 5) & 1023;
    int head = t >> 15;
    int base = (head * 1024 + row) * 2;
    float m0 = mlpart[base * 2],     l0 = mlpart[base * 2 + 1];
    float m1 = mlpart[base * 2 + 2], l1 = mlpart[base * 2 + 3];
    float m = fmaxf(m0, m1);
    float a0 = __builtin_amdgcn_exp2f(m0 - m);
    float a1 = __builtin_amdgcn_exp2f(m1 - m);
    float inv = 1.0f / (l0 * a0 + l1 * a1);
    f32x4 o0 = *(const f32x4*)&opart[(size_t)base * 128 + d4 * 4];
    f32x4 o1 = *(const f32x4*)&opart[(size_t)(base + 1) * 128 + d4 * 4];
    bf16x4v ov;
#pragma unroll
    for (int c = 0; c < 4; ++c) ov[c] = (bf16_t)((o0[c] * a0 + o1[c] * a1) * inv);
    *(bf16x4v*)&o_out[(size_t)(1024 + row) * HIDDEN + head * HDIM + d4 * 4] = ov;
}

extern "C" void kernel_launch(void* const* d_in, const int* in_sizes, int n_in,
                              void* d_out, int out_size, void* d_ws, size_t ws_size,
                              hipStream_t stream) {
    const float* hs   = (const float*)d_in[0];
    const float* cosb = (const float*)d_in[1];
    const float* sinb = (const float*)d_in[2];
    const float* Wq   = (const float*)d_in[3];
    const float* bq   = (const float*)d_in[4];
    const float* Wk   = (const float*)d_in[5];
    const float* bk   = (const float*)d_in[6];
    const float* Wv   = (const float*)d_in[7];
    const float* bv   = (const float*)d_in[8];
    const float* Wo   = (const float*)d_in[9];
    float* out = (float*)d_out;

    char* p = (char*)d_ws;
    bf16_t* hsb   = (bf16_t*)p; p += (size_t)SEQ * HIDDEN * 2;        // also reused as attn out
    bf16_t* Wqkvb = (bf16_t*)p; p += (size_t)QKV_LD * HIDDEN * 2;
    bf16_t* Wob   = (bf16_t*)p; p += (size_t)HIDDEN * HIDDEN * 2;
    bf16_t* qkvb  = (bf16_t*)p; p += (size_t)SEQ * QKV_LD * 2;
    float*  bcat  = (float*)p;  p += (size_t)QKV_LD * 4;

    // attn partials overlay the Wqkvb region (dead after gemm1):
    // opart: 28*1024*2*128 f32 = 29.36 MB, mlpart: 28*1024*2*2 f32 = 0.46 MB  (< 33.03 MB)
    float* opart  = (float*)Wqkvb;
    float* mlpart = opart + (size_t)NHEADS * 1024 * 2 * 128;

    const int total_f4 = HS_F4 + WQ_F4 + WK_F4 + WV_F4 + WO_F4;
    cvt_all_kernel<<<(total_f4 + 255) / 256, 256, 0, stream>>>(
        hs, Wq, Wk, Wv, Wo, hsb, Wqkvb, Wob);
    bcat_kernel<<<(QKV_LD + 255) / 256, 256, 0, stream>>>(bq, bk, bv, bcat);

    gemm_bt<true><<<dim3(QKV_LD / 128, SEQ / 128), 256, 0, stream>>>(
        hsb, Wqkvb, bcat, qkvb, SEQ, QKV_LD, HIDDEN);

    rope_kernel<<<(SEQ * 32 * 64) / 256, 256, 0, stream>>>(qkvb, cosb, sinb);

    attn_kernel<<<dim3(24, NHEADS), 512, 0, stream>>>(qkvb, hsb, opart, mlpart);
    combine_kernel<<<NHEADS * 1024 * 32 / 256, 256, 0, stream>>>(opart, mlpart, hsb);

    gemm_bt<false><<<dim3(HIDDEN / 128, SEQ / 128), 256, 0, stream>>>(
        hsb, Wob, nullptr, out, SEQ, HIDDEN, HIDDEN);
}

// Round 6
// 473.552 us; speedup vs baseline: 1.1034x; 1.0050x over previous
//
#include <hip/hip_runtime.h>
#include <hip/hip_bf16.h>

typedef __bf16 bf16_t;
typedef __bf16 bf16x8 __attribute__((ext_vector_type(8)));
typedef __bf16 bf16x4v __attribute__((ext_vector_type(4)));
typedef float f32x4 __attribute__((ext_vector_type(4)));

#define HIDDEN 3584
#define SEQ 2048
#define NHEADS 28
#define NKV 4
#define HDIM 128
#define GROUPS 7
#define QKV_LD 4608
#define SCL_LOG2 (0.08838834764831845f * 1.44269504088896f)

__device__ inline f32x4 mfma16(bf16x8 a, bf16x8 b, f32x4 c) {
    return __builtin_amdgcn_mfma_f32_16x16x32_bf16(a, b, c, 0, 0, 0);
}

__device__ inline void gl_lds16(const bf16_t* g, bf16_t* l) {
    __builtin_amdgcn_global_load_lds(
        (const __attribute__((address_space(1))) void*)g,
        (__attribute__((address_space(3))) void*)l, 16, 0, 0);
}

// ---------------- fused fp32 -> bf16 convert (all 5 tensors, 1 dispatch) ----------------
#define HS_F4   1835008   // 2048*3584/4
#define WQ_F4   3211264   // 3584*3584/4
#define WK_F4    458752   // 512*3584/4
#define WV_F4    458752
#define WO_F4   3211264
__global__ void cvt_all_kernel(const float* __restrict__ hs, const float* __restrict__ Wq,
                               const float* __restrict__ Wk, const float* __restrict__ Wv,
                               const float* __restrict__ Wo,
                               bf16_t* __restrict__ hsb, bf16_t* __restrict__ Wqkvb,
                               bf16_t* __restrict__ Wob) {
    int i = blockIdx.x * 256 + threadIdx.x;
    const float* s; bf16_t* d; int off;
    if (i < HS_F4) { s = hs; d = hsb; off = i; }
    else if (i < HS_F4 + WQ_F4) { s = Wq; d = Wqkvb; off = i - HS_F4; }
    else if (i < HS_F4 + WQ_F4 + WK_F4) { s = Wk; d = Wqkvb + 4 * (size_t)WQ_F4; off = i - HS_F4 - WQ_F4; }
    else if (i < HS_F4 + WQ_F4 + WK_F4 + WV_F4) { s = Wv; d = Wqkvb + 4 * ((size_t)WQ_F4 + WK_F4); off = i - HS_F4 - WQ_F4 - WK_F4; }
    else { s = Wo; d = Wob; off = i - HS_F4 - WQ_F4 - WK_F4 - WV_F4; }
    float4 f = ((const float4*)s)[off];
    bf16x4v o;
    o.x = (bf16_t)f.x; o.y = (bf16_t)f.y; o.z = (bf16_t)f.z; o.w = (bf16_t)f.w;
    ((bf16x4v*)d)[off] = o;
}

// ---------------- bias concat (bq|bk|bv) ----------------
__global__ void bcat_kernel(const float* __restrict__ bq, const float* __restrict__ bk,
                            const float* __restrict__ bv, float* __restrict__ dst) {
    int i = blockIdx.x * 256 + threadIdx.x;
    if (i < QKV_LD) {
        float v = (i < HIDDEN) ? bq[i] : (i < HIDDEN + 512 ? bk[i - HIDDEN] : bv[i - HIDDEN - 512]);
        dst[i] = v;
    }
}

// ---------------- GEMM: C[M,N] = A[M,K] @ B[N,K]^T (+bias) ----------------
// 128x128 tile, BK=64 staged as 2 x 32-col panels (m97 geometry per panel).
template <bool OUT_BF16>
__global__ __launch_bounds__(256) void gemm_bt(
    const bf16_t* __restrict__ A, const bf16_t* __restrict__ B,
    const float* __restrict__ bias, void* __restrict__ Cout,
    int M, int N, int K) {
    __shared__ __align__(16) bf16_t As[2][128 * 32];
    __shared__ __align__(16) bf16_t Bs[2][128 * 32];
    const int tid = threadIdx.x;
    const int w = tid >> 6, lane = tid & 63;
    const int quad = lane >> 4, l16 = lane & 15;
    const int wm = w >> 1, wn = w & 1;
    const int m0 = blockIdx.y * 128, n0 = blockIdx.x * 128;
    f32x4 acc[4][4] = {};
    for (int k0 = 0; k0 < K; k0 += 64) {
        __syncthreads();
#pragma unroll
        for (int p = 0; p < 2; ++p)
#pragma unroll
            for (int i = 0; i < 2; ++i) {
                int ca = (w * 2 + i) * 64 + lane;          // chunk 0..511 within panel
                int row = ca >> 2, kc = ca & 3;
                gl_lds16(A + (size_t)(m0 + row) * K + k0 + p * 32 + kc * 8,
                         As[p] + (size_t)(w * 2 + i) * 512);
                gl_lds16(B + (size_t)(n0 + row) * K + k0 + p * 32 + kc * 8,
                         Bs[p] + (size_t)(w * 2 + i) * 512);
            }
        __syncthreads();
#pragma unroll
        for (int p = 0; p < 2; ++p) {
            bf16x8 a[4], b[4];
#pragma unroll
            for (int i = 0; i < 4; ++i)
                a[i] = *(const bf16x8*)(As[p] + (wm * 64 + i * 16 + l16) * 32 + quad * 8);
#pragma unroll
            for (int j = 0; j < 4; ++j)
                b[j] = *(const bf16x8*)(Bs[p] + (wn * 64 + j * 16 + l16) * 32 + quad * 8);
#pragma unroll
            for (int i = 0; i < 4; ++i)
#pragma unroll
                for (int j = 0; j < 4; ++j)
                    acc[i][j] = mfma16(a[i], b[j], acc[i][j]);
        }
    }
#pragma unroll
    for (int i = 0; i < 4; ++i) {
#pragma unroll
        for (int j = 0; j < 4; ++j) {
            int col = n0 + wn * 64 + j * 16 + l16;
            float bv_ = bias ? bias[col] : 0.f;
#pragma unroll
            for (int r = 0; r < 4; ++r) {
                int row = m0 + wm * 64 + i * 16 + quad * 4 + r;
                float v = acc[i][j][r] + bv_;
                if (OUT_BF16) ((bf16_t*)Cout)[(size_t)row * N + col] = (bf16_t)v;
                else          ((float*)Cout)[(size_t)row * N + col] = v;
            }
        }
    }
}

// ---------------- RoPE (in-place on bf16 qkv buffer) ----------------
__global__ void rope_kernel(bf16_t* __restrict__ qkv,
                            const float* __restrict__ cosb, const float* __restrict__ sinb) {
    int t = blockIdx.x * 256 + threadIdx.x;   // SEQ * 32 * 64 total
    int d = t & 63;
    int hh = (t >> 6) & 31;
    int s = t >> 11;
    float c0 = cosb[s * 128 + d], sn0 = sinb[s * 128 + d];
    float c1 = cosb[s * 128 + d + 64], sn1 = sinb[s * 128 + d + 64];
    bf16_t* p;
    if (hh < NHEADS) p = qkv + (size_t)s * QKV_LD + hh * HDIM;
    else             p = qkv + (size_t)s * QKV_LD + HIDDEN + (hh - NHEADS) * HDIM;
    float x0 = (float)p[d], x1 = (float)p[d + 64];
    p[d]      = (bf16_t)(x0 * c0 - x1 * sn0);
    p[d + 64] = (bf16_t)(x1 * c1 + x0 * sn1);
}

// ---------------- Flash attention (R5 schedule + conflict-free aligned LDS swizzles) ----------
// 512 threads = 8 waves = 2 groups x 4 waves; groups share K/V staging.
// grid (24, NHEADS):
//   bx 0..7  : unsplit; group0 qb=15-bx, group1 qb=bx; kv tiles 0..qb step 1 -> bf16 out
//   bx 8..23 : split; idx=bx-8, parity=idx>>3, j=idx&7; group0 qb=31-j, group1 qb=16+j;
//              kv tiles parity, parity+2, ... -> f32 partials (m,l,unnormalized O) -> combine
// LDS (changed from R5): linear power-of-2 strides + XOR 16B-chunk swizzles, all accesses
// 16B-aligned and bank-optimal (8 lanes/bank-group, 8 dwords/bank = hw minimum):
//   Ks[64][128]: elem(r,c) at r*128 + 8*((c>>3) ^ ((r&3)|((r>>1)&4))) + (c&7); QK key = l16&7
//   Vt[128][64]: elem(d,kv) at d*64 + 8*(((kv>>3) ^ (d&7))) + (kv&7);        PV key = l16&7
// kv fragment-row permutation: F(st,m) = 32*(st>>1) + 8*(m>>2) + 4*(st&1) + (m&3)
__global__ __launch_bounds__(512, 4) void attn_kernel(
    const bf16_t* __restrict__ qkv, bf16_t* __restrict__ o_out,
    float* __restrict__ opart, float* __restrict__ mlpart) {
    __shared__ __align__(16) bf16_t Ks[64 * 128];
    __shared__ __align__(16) bf16_t Vt[128 * 64];
    const int tid = threadIdx.x;
    const int w = tid >> 6, lane = tid & 63;
    const int quad = lane >> 4, l16 = lane & 15;
    const int wq = w & 3;                 // wave index within its q-tile group
    const int grp = w >> 2;               // 0 = long tile, 1 = short tile
    const int h = blockIdx.y, kvh = h / GROUPS;
    const int bx = blockIdx.x;

    int qb0, qb1, kbase, kstep; bool split;
    if (bx < 8) { split = false; kbase = 0; kstep = 1; qb0 = 15 - bx; qb1 = bx; }
    else { split = true; int idx = bx - 8; kbase = idx >> 3; kstep = 2;
           int j = idx & 7; qb0 = 31 - j; qb1 = 16 + j; }

    const int qb   = grp ? qb1 : qb0;
    const int n_me = (qb  - kbase) / kstep + 1;   // this group's compute-tile count
    const int ntk  = (qb0 - kbase) / kstep + 1;   // staged tiles (group0 is the long one)

    const bf16_t* qp = qkv + h * HDIM;
    const bf16_t* kp = qkv + HIDDEN + kvh * HDIM;
    const bf16_t* vp = qkv + HIDDEN + 512 + kvh * HDIM;
    const int fk = l16 & 7;               // read-side swizzle key (both Ks and Vt)
    int frow[4];
#pragma unroll
    for (int st = 0; st < 4; ++st)
        frow[st] = 32 * (st >> 1) + 8 * (l16 >> 2) + 4 * (st & 1) + (l16 & 3);
    const int vc0 = (quad ^ fk) << 3;         // Vt column offsets (loop-invariant)
    const int vc1 = ((quad + 4) ^ fk) << 3;

    const int rowq = qb * 64 + wq * 16 + l16;   // this lane's q-row (as column of S^T)
    bf16x8 qa[4];
#pragma unroll
    for (int kc = 0; kc < 4; ++kc)
        qa[kc] = *(const bf16x8*)(qp + (size_t)rowq * QKV_LD + kc * 32 + quad * 8);
    f32x4 o[8] = {};
    float m_r = -1.0e30f, l_r = 0.f;

    int4 kr[2], vr[2];
    auto loadT = [&](int kv0) {
#pragma unroll
        for (int i = 0; i < 2; ++i)
            kr[i] = *(const int4*)(kp + (size_t)(kv0 + (w * 2 + i) * 4 + quad) * QKV_LD + l16 * 8);
#pragma unroll
        for (int i = 0; i < 2; ++i)
            vr[i] = *(const int4*)(vp + (size_t)(kv0 + lane) * QKV_LD + (w * 2 + i) * 8);
    };
    loadT(kbase * 64);

    for (int it = 0; it < ntk; ++it) {
        const int kv0 = (kbase + kstep * it) * 64;
        __syncthreads();
        // ---- stage K: row r, source chunk l16, swizzled chunk l16^key(r) ----
#pragma unroll
        for (int i = 0; i < 2; ++i) {
            int r = (w * 2 + i) * 4 + quad;
            int key = (r & 3) | ((r >> 1) & 4);
            *(int4*)&Ks[r * 128 + ((l16 ^ key) << 3)] = kr[i];
        }
        // ---- stage V^T: row d (wave-uniform per write), per-lane kv=lane ----
#pragma unroll
        for (int i = 0; i < 2; ++i) {
            bf16_t* ts = (bf16_t*)&vr[i];
#pragma unroll
            for (int i2 = 0; i2 < 8; ++i2) {
                int d = (w * 2 + i) * 8 + i2;
                Vt[d * 64 + (((lane >> 3) ^ (d & 7)) << 3) + (lane & 7)] = ts[i2];
            }
        }
        __syncthreads();
        if (it + 1 < ntk) loadT((kbase + kstep * (it + 1)) * 64);   // prefetch overlaps compute
        if (it < n_me) {
            f32x4 s[4] = {};
#pragma unroll
            for (int kc = 0; kc < 4; ++kc)
#pragma unroll
                for (int st = 0; st < 4; ++st) {
                    bf16x8 kb = *(const bf16x8*)&Ks[frow[st] * 128 + ((((kc << 2) + quad) ^ fk) << 3)];
                    s[st] = mfma16(kb, qa[kc], s[st]);
                }
            const bool diag = ((kv0 >> 6) == qb);   // tile containing the causal diagonal
            float xv[4][4], mx = -1.0e30f;
#pragma unroll
            for (int st = 0; st < 4; ++st)
#pragma unroll
                for (int r = 0; r < 4; ++r) {
                    int kvg = kv0 + 32 * (st >> 1) + 8 * quad + 4 * (st & 1) + r;
                    float x = s[st][r] * SCL_LOG2;
                    if (diag && kvg > rowq) x = -1.0e30f;
                    xv[st][r] = x;
                    mx = fmaxf(mx, x);
                }
            mx = fmaxf(mx, __shfl_xor(mx, 16));
            mx = fmaxf(mx, __shfl_xor(mx, 32));
            float mn = fmaxf(m_r, mx);
            float al = __builtin_amdgcn_exp2f(m_r - mn);
            m_r = mn;
            float rs = 0.f;
            bf16x8 pb0, pb1;
#pragma unroll
            for (int r = 0; r < 4; ++r) {
                float p00 = __builtin_amdgcn_exp2f(xv[0][r] - mn);
                float p01 = __builtin_amdgcn_exp2f(xv[1][r] - mn);
                float p10 = __builtin_amdgcn_exp2f(xv[2][r] - mn);
                float p11 = __builtin_amdgcn_exp2f(xv[3][r] - mn);
                rs += (p00 + p01) + (p10 + p11);
                pb0[r] = (bf16_t)p00; pb0[4 + r] = (bf16_t)p01;
                pb1[r] = (bf16_t)p10; pb1[4 + r] = (bf16_t)p11;
            }
            rs += __shfl_xor(rs, 16);
            rs += __shfl_xor(rs, 32);
            l_r = al * l_r + rs;
#pragma unroll
            for (int dd = 0; dd < 8; ++dd) {
#pragma unroll
                for (int r = 0; r < 4; ++r) o[dd][r] *= al;
                const int dr = dd * 16 + l16;
                bf16x8 va0 = *(const bf16x8*)&Vt[dr * 64 + vc0];
                bf16x8 va1 = *(const bf16x8*)&Vt[dr * 64 + vc1];
                o[dd] = mfma16(va1, pb1, mfma16(va0, pb0, o[dd]));
            }
        }
    }
    if (!split) {
        float inv_l = 1.0f / l_r;
#pragma unroll
        for (int dd = 0; dd < 8; ++dd) {
            bf16x4v ov;
#pragma unroll
            for (int r = 0; r < 4; ++r) ov[r] = (bf16_t)(o[dd][r] * inv_l);
            *(bf16x4v*)&o_out[(size_t)rowq * HIDDEN + h * HDIM + dd * 16 + quad * 4] = ov;
        }
    } else {
        // unnormalized f32 partials; rows 1024..2047; parity = kbase
        const int prow = (h * 1024 + (rowq - 1024)) * 2 + kbase;
        float* op = opart + (size_t)prow * 128;
#pragma unroll
        for (int dd = 0; dd < 8; ++dd)
            *(f32x4*)&op[dd * 16 + quad * 4] = o[dd];
        if (quad == 0) {
            mlpart[prow * 2]     = m_r;
            mlpart[prow * 2 + 1] = l_r;
        }
    }
}

// ---------------- combine the two kv-parity partials for q rows 1024..2047 ----------------
__global__ void combine_kernel(const float* __restrict__ opart, const float* __restrict__ mlpart,
                               bf16_t* __restrict__ o_out) {
    int t = blockIdx.x * 256 + threadIdx.x;   // 28*1024*32 = 917504
    int d4 = t & 31;
    int row = (t >> 5) & 1023;
    int head = t >> 15;
    int base = (head * 1024 + row) * 2;
    float m0 = mlpart[base * 2],     l0 = mlpart[base * 2 + 1];
    float m1 = mlpart[base * 2 + 2], l1 = mlpart[base * 2 + 3];
    float m = fmaxf(m0, m1);
    float a0 = __builtin_amdgcn_exp2f(m0 - m);
    float a1 = __builtin_amdgcn_exp2f(m1 - m);
    float inv = 1.0f / (l0 * a0 + l1 * a1);
    f32x4 o0 = *(const f32x4*)&opart[(size_t)base * 128 + d4 * 4];
    f32x4 o1 = *(const f32x4*)&opart[(size_t)(base + 1) * 128 + d4 * 4];
    bf16x4v ov;
#pragma unroll
    for (int c = 0; c < 4; ++c) ov[c] = (bf16_t)((o0[c] * a0 + o1[c] * a1) * inv);
    *(bf16x4v*)&o_out[(size_t)(1024 + row) * HIDDEN + head * HDIM + d4 * 4] = ov;
}

extern "C" void kernel_launch(void* const* d_in, const int* in_sizes, int n_in,
                              void* d_out, int out_size, void* d_ws, size_t ws_size,
                              hipStream_t stream) {
    const float* hs   = (const float*)d_in[0];
    const float* cosb = (const float*)d_in[1];
    const float* sinb = (const float*)d_in[2];
    const float* Wq   = (const float*)d_in[3];
    const float* bq   = (const float*)d_in[4];
    const float* Wk   = (const float*)d_in[5];
    const float* bk   = (const float*)d_in[6];
    const float* Wv   = (const float*)d_in[7];
    const float* bv   = (const float*)d_in[8];
    const float* Wo   = (const float*)d_in[9];
    float* out = (float*)d_out;

    char* p = (char*)d_ws;
    bf16_t* hsb   = (bf16_t*)p; p += (size_t)SEQ * HIDDEN * 2;        // also reused as attn out
    bf16_t* Wqkvb = (bf16_t*)p; p += (size_t)QKV_LD * HIDDEN * 2;
    bf16_t* Wob   = (bf16_t*)p; p += (size_t)HIDDEN * HIDDEN * 2;
    bf16_t* qkvb  = (bf16_t*)p; p += (size_t)SEQ * QKV_LD * 2;
    float*  bcat  = (float*)p;  p += (size_t)QKV_LD * 4;

    // attn partials overlay the Wqkvb region (dead after gemm1):
    // opart: 28*1024*2*128 f32 = 29.36 MB, mlpart: 28*1024*2*2 f32 = 0.46 MB  (< 33.03 MB)
    float* opart  = (float*)Wqkvb;
    float* mlpart = opart + (size_t)NHEADS * 1024 * 2 * 128;

    const int total_f4 = HS_F4 + WQ_F4 + WK_F4 + WV_F4 + WO_F4;
    cvt_all_kernel<<<(total_f4 + 255) / 256, 256, 0, stream>>>(
        hs, Wq, Wk, Wv, Wo, hsb, Wqkvb, Wob);
    bcat_kernel<<<(QKV_LD + 255) / 256, 256, 0, stream>>>(bq, bk, bv, bcat);

    gemm_bt<true><<<dim3(QKV_LD / 128, SEQ / 128), 256, 0, stream>>>(
        hsb, Wqkvb, bcat, qkvb, SEQ, QKV_LD, HIDDEN);

    rope_kernel<<<(SEQ * 32 * 64) / 256, 256, 0, stream>>>(qkvb, cosb, sinb);

    attn_kernel<<<dim3(24, NHEADS), 512, 0, stream>>>(qkvb, hsb, opart, mlpart);
    combine_kernel<<<NHEADS * 1024 * 32 / 256, 256, 0, stream>>>(opart, mlpart, hsb);

    gemm_bt<false><<<dim3(HIDDEN / 128, SEQ / 128), 256, 0, stream>>>(
        hsb, Wob, nullptr, out, SEQ, HIDDEN, HIDDEN);
}

// Round 7
// 467.945 us; speedup vs baseline: 1.1166x; 1.0120x over previous
//
#include <hip/hip_runtime.h>
#include <hip/hip_bf16.h>

typedef __bf16 bf16_t;
typedef __bf16 bf16x8 __attribute__((ext_vector_type(8)));
typedef __bf16 bf16x4v __attribute__((ext_vector_type(4)));
typedef float f32x4 __attribute__((ext_vector_type(4)));

#define HIDDEN 3584
#define SEQ 2048
#define NHEADS 28
#define NKV 4
#define HDIM 128
#define GROUPS 7
#define QKV_LD 4608
#define SCL_LOG2 (0.08838834764831845f * 1.44269504088896f)

__device__ inline f32x4 mfma16(bf16x8 a, bf16x8 b, f32x4 c) {
    return __builtin_amdgcn_mfma_f32_16x16x32_bf16(a, b, c, 0, 0, 0);
}

__device__ inline void gl_lds16(const bf16_t* g, bf16_t* l) {
    __builtin_amdgcn_global_load_lds(
        (const __attribute__((address_space(1))) void*)g,
        (__attribute__((address_space(3))) void*)l, 16, 0, 0);
}

// ---------------- fused fp32 -> bf16 convert (5 tensors) + bias concat, 1 dispatch ----------------
#define HS_F4   1835008   // 2048*3584/4
#define WQ_F4   3211264   // 3584*3584/4
#define WK_F4    458752   // 512*3584/4
#define WV_F4    458752
#define WO_F4   3211264
#define B_F4    1152      // 4608/4 bias floats (f32 passthrough)
__global__ void cvt_all_kernel(const float* __restrict__ hs, const float* __restrict__ Wq,
                               const float* __restrict__ Wk, const float* __restrict__ Wv,
                               const float* __restrict__ Wo,
                               const float* __restrict__ bq, const float* __restrict__ bk,
                               const float* __restrict__ bv,
                               bf16_t* __restrict__ hsb, bf16_t* __restrict__ Wqkvb,
                               bf16_t* __restrict__ Wob, float* __restrict__ bcat) {
    int i = blockIdx.x * 256 + threadIdx.x;
    const int T4 = HS_F4 + WQ_F4 + WK_F4 + WV_F4 + WO_F4;
    if (i >= T4) {           // bias concat tail (f32 -> f32), segments are float4-aligned
        int i2 = i - T4;
        if (i2 < B_F4) {
            float4 f = (i2 < 896) ? ((const float4*)bq)[i2]
                     : (i2 < 1024) ? ((const float4*)bk)[i2 - 896]
                                   : ((const float4*)bv)[i2 - 1024];
            ((float4*)bcat)[i2] = f;
        }
        return;
    }
    const float* s; bf16_t* d; int off;
    if (i < HS_F4) { s = hs; d = hsb; off = i; }
    else if (i < HS_F4 + WQ_F4) { s = Wq; d = Wqkvb; off = i - HS_F4; }
    else if (i < HS_F4 + WQ_F4 + WK_F4) { s = Wk; d = Wqkvb + 4 * (size_t)WQ_F4; off = i - HS_F4 - WQ_F4; }
    else if (i < HS_F4 + WQ_F4 + WK_F4 + WV_F4) { s = Wv; d = Wqkvb + 4 * ((size_t)WQ_F4 + WK_F4); off = i - HS_F4 - WQ_F4 - WK_F4; }
    else { s = Wo; d = Wob; off = i - HS_F4 - WQ_F4 - WK_F4 - WV_F4; }
    float4 f = ((const float4*)s)[off];
    bf16x4v o;
    o.x = (bf16_t)f.x; o.y = (bf16_t)f.y; o.z = (bf16_t)f.z; o.w = (bf16_t)f.w;
    ((bf16x4v*)d)[off] = o;
}

// ---------------- GEMM: C[M,N] = A[M,K] @ B[N,K]^T (+bias) ----------------
// 128x128 tile, BK=64 staged as 2 x 32-col panels (m97 geometry per panel).
template <bool OUT_BF16>
__global__ __launch_bounds__(256) void gemm_bt(
    const bf16_t* __restrict__ A, const bf16_t* __restrict__ B,
    const float* __restrict__ bias, void* __restrict__ Cout,
    int M, int N, int K) {
    __shared__ __align__(16) bf16_t As[2][128 * 32];
    __shared__ __align__(16) bf16_t Bs[2][128 * 32];
    const int tid = threadIdx.x;
    const int w = tid >> 6, lane = tid & 63;
    const int quad = lane >> 4, l16 = lane & 15;
    const int wm = w >> 1, wn = w & 1;
    const int m0 = blockIdx.y * 128, n0 = blockIdx.x * 128;
    f32x4 acc[4][4] = {};
    for (int k0 = 0; k0 < K; k0 += 64) {
        __syncthreads();
#pragma unroll
        for (int p = 0; p < 2; ++p)
#pragma unroll
            for (int i = 0; i < 2; ++i) {
                int ca = (w * 2 + i) * 64 + lane;          // chunk 0..511 within panel
                int row = ca >> 2, kc = ca & 3;
                gl_lds16(A + (size_t)(m0 + row) * K + k0 + p * 32 + kc * 8,
                         As[p] + (size_t)(w * 2 + i) * 512);
                gl_lds16(B + (size_t)(n0 + row) * K + k0 + p * 32 + kc * 8,
                         Bs[p] + (size_t)(w * 2 + i) * 512);
            }
        __syncthreads();
#pragma unroll
        for (int p = 0; p < 2; ++p) {
            bf16x8 a[4], b[4];
#pragma unroll
            for (int i = 0; i < 4; ++i)
                a[i] = *(const bf16x8*)(As[p] + (wm * 64 + i * 16 + l16) * 32 + quad * 8);
#pragma unroll
            for (int j = 0; j < 4; ++j)
                b[j] = *(const bf16x8*)(Bs[p] + (wn * 64 + j * 16 + l16) * 32 + quad * 8);
#pragma unroll
            for (int i = 0; i < 4; ++i)
#pragma unroll
                for (int j = 0; j < 4; ++j)
                    acc[i][j] = mfma16(a[i], b[j], acc[i][j]);
        }
    }
#pragma unroll
    for (int i = 0; i < 4; ++i) {
#pragma unroll
        for (int j = 0; j < 4; ++j) {
            int col = n0 + wn * 64 + j * 16 + l16;
            float bv_ = bias ? bias[col] : 0.f;
#pragma unroll
            for (int r = 0; r < 4; ++r) {
                int row = m0 + wm * 64 + i * 16 + quad * 4 + r;
                float v = acc[i][j][r] + bv_;
                if (OUT_BF16) ((bf16_t*)Cout)[(size_t)row * N + col] = (bf16_t)v;
                else          ((float*)Cout)[(size_t)row * N + col] = v;
            }
        }
    }
}

// ---------------- RoPE (in-place on bf16 qkv buffer) ----------------
__global__ void rope_kernel(bf16_t* __restrict__ qkv,
                            const float* __restrict__ cosb, const float* __restrict__ sinb) {
    int t = blockIdx.x * 256 + threadIdx.x;   // SEQ * 32 * 64 total
    int d = t & 63;
    int hh = (t >> 6) & 31;
    int s = t >> 11;
    float c0 = cosb[s * 128 + d], sn0 = sinb[s * 128 + d];
    float c1 = cosb[s * 128 + d + 64], sn1 = sinb[s * 128 + d + 64];
    bf16_t* p;
    if (hh < NHEADS) p = qkv + (size_t)s * QKV_LD + hh * HDIM;
    else             p = qkv + (size_t)s * QKV_LD + HIDDEN + (hh - NHEADS) * HDIM;
    float x0 = (float)p[d], x1 = (float)p[d + 64];
    p[d]      = (bf16_t)(x0 * c0 - x1 * sn0);
    p[d + 64] = (bf16_t)(x1 * c1 + x0 * sn1);
}

// ---------------- Flash attention (R6 + T13 defer-max + T5 setprio) ----------
// 512 threads = 8 waves = 2 groups x 4 waves; groups share K/V staging.
// grid (24, NHEADS):
//   bx 0..7  : unsplit; group0 qb=15-bx, group1 qb=bx; kv tiles 0..qb step 1 -> bf16 out
//   bx 8..23 : split; idx=bx-8, parity=idx>>3, j=idx&7; group0 qb=31-j, group1 qb=16+j;
//              kv tiles parity, parity+2, ... -> f32 partials (m,l,unnormalized O) -> combine
// LDS: linear power-of-2 strides + XOR 16B-chunk swizzles (R6-verified):
//   Ks[64][128]: elem(r,c) at r*128 + 8*((c>>3) ^ ((r&3)|((r>>1)&4))) + (c&7); QK key = l16&7
//   Vt[128][64]: elem(d,kv) at d*64 + 8*(((kv>>3) ^ (d&7))) + (kv&7);        PV key = l16&7
// kv fragment-row permutation: F(st,m) = 32*(st>>1) + 8*(m>>2) + 4*(st&1) + (m&3)
__global__ __launch_bounds__(512, 4) void attn_kernel(
    const bf16_t* __restrict__ qkv, bf16_t* __restrict__ o_out,
    float* __restrict__ opart, float* __restrict__ mlpart) {
    __shared__ __align__(16) bf16_t Ks[64 * 128];
    __shared__ __align__(16) bf16_t Vt[128 * 64];
    const int tid = threadIdx.x;
    const int w = tid >> 6, lane = tid & 63;
    const int quad = lane >> 4, l16 = lane & 15;
    const int wq = w & 3;                 // wave index within its q-tile group
    const int grp = w >> 2;               // 0 = long tile, 1 = short tile
    const int h = blockIdx.y, kvh = h / GROUPS;
    const int bx = blockIdx.x;

    int qb0, qb1, kbase, kstep; bool split;
    if (bx < 8) { split = false; kbase = 0; kstep = 1; qb0 = 15 - bx; qb1 = bx; }
    else { split = true; int idx = bx - 8; kbase = idx >> 3; kstep = 2;
           int j = idx & 7; qb0 = 31 - j; qb1 = 16 + j; }

    const int qb   = grp ? qb1 : qb0;
    const int n_me = (qb  - kbase) / kstep + 1;   // this group's compute-tile count
    const int ntk  = (qb0 - kbase) / kstep + 1;   // staged tiles (group0 is the long one)

    const bf16_t* qp = qkv + h * HDIM;
    const bf16_t* kp = qkv + HIDDEN + kvh * HDIM;
    const bf16_t* vp = qkv + HIDDEN + 512 + kvh * HDIM;
    const int fk = l16 & 7;               // read-side swizzle key (both Ks and Vt)
    int frow[4];
#pragma unroll
    for (int st = 0; st < 4; ++st)
        frow[st] = 32 * (st >> 1) + 8 * (l16 >> 2) + 4 * (st & 1) + (l16 & 3);
    const int vc0 = (quad ^ fk) << 3;         // Vt column offsets (loop-invariant)
    const int vc1 = ((quad + 4) ^ fk) << 3;

    const int rowq = qb * 64 + wq * 16 + l16;   // this lane's q-row (as column of S^T)
    bf16x8 qa[4];
#pragma unroll
    for (int kc = 0; kc < 4; ++kc)
        qa[kc] = *(const bf16x8*)(qp + (size_t)rowq * QKV_LD + kc * 32 + quad * 8);
    f32x4 o[8] = {};
    float m_r = -1.0e30f, l_r = 0.f;

    int4 kr[2], vr[2];
    auto loadT = [&](int kv0) {
#pragma unroll
        for (int i = 0; i < 2; ++i)
            kr[i] = *(const int4*)(kp + (size_t)(kv0 + (w * 2 + i) * 4 + quad) * QKV_LD + l16 * 8);
#pragma unroll
        for (int i = 0; i < 2; ++i)
            vr[i] = *(const int4*)(vp + (size_t)(kv0 + lane) * QKV_LD + (w * 2 + i) * 8);
    };
    loadT(kbase * 64);

    for (int it = 0; it < ntk; ++it) {
        const int kv0 = (kbase + kstep * it) * 64;
        __syncthreads();
        // ---- stage K: row r, source chunk l16, swizzled chunk l16^key(r) ----
#pragma unroll
        for (int i = 0; i < 2; ++i) {
            int r = (w * 2 + i) * 4 + quad;
            int key = (r & 3) | ((r >> 1) & 4);
            *(int4*)&Ks[r * 128 + ((l16 ^ key) << 3)] = kr[i];
        }
        // ---- stage V^T: row d (wave-uniform per write), per-lane kv=lane ----
#pragma unroll
        for (int i = 0; i < 2; ++i) {
            bf16_t* ts = (bf16_t*)&vr[i];
#pragma unroll
            for (int i2 = 0; i2 < 8; ++i2) {
                int d = (w * 2 + i) * 8 + i2;
                Vt[d * 64 + (((lane >> 3) ^ (d & 7)) << 3) + (lane & 7)] = ts[i2];
            }
        }
        __syncthreads();
        if (it + 1 < ntk) loadT((kbase + kstep * (it + 1)) * 64);   // prefetch overlaps compute
        if (it < n_me) {
            f32x4 s[4] = {};
            __builtin_amdgcn_s_setprio(1);
#pragma unroll
            for (int kc = 0; kc < 4; ++kc)
#pragma unroll
                for (int st = 0; st < 4; ++st) {
                    bf16x8 kb = *(const bf16x8*)&Ks[frow[st] * 128 + ((((kc << 2) + quad) ^ fk) << 3)];
                    s[st] = mfma16(kb, qa[kc], s[st]);
                }
            __builtin_amdgcn_s_setprio(0);
            const bool diag = ((kv0 >> 6) == qb);   // tile containing the causal diagonal
            float xv[4][4], mx = -1.0e30f;
#pragma unroll
            for (int st = 0; st < 4; ++st)
#pragma unroll
                for (int r = 0; r < 4; ++r) {
                    int kvg = kv0 + 32 * (st >> 1) + 8 * quad + 4 * (st & 1) + r;
                    float x = s[st][r] * SCL_LOG2;
                    if (diag && kvg > rowq) x = -1.0e30f;
                    xv[st][r] = x;
                    mx = fmaxf(mx, x);
                }
            mx = fmaxf(mx, __shfl_xor(mx, 16));
            mx = fmaxf(mx, __shfl_xor(mx, 32));
            // T13 defer-max: only rescale when the running max grows beyond 2^8 (log2 domain)
            if (__any(mx > m_r + 8.0f)) {
                float mn = fmaxf(m_r, mx);
                float al = __builtin_amdgcn_exp2f(m_r - mn);
                m_r = mn;
                l_r *= al;
#pragma unroll
                for (int dd = 0; dd < 8; ++dd)
#pragma unroll
                    for (int r = 0; r < 4; ++r) o[dd][r] *= al;
            }
            float rs = 0.f;
            bf16x8 pb0, pb1;
#pragma unroll
            for (int r = 0; r < 4; ++r) {
                float p00 = __builtin_amdgcn_exp2f(xv[0][r] - m_r);
                float p01 = __builtin_amdgcn_exp2f(xv[1][r] - m_r);
                float p10 = __builtin_amdgcn_exp2f(xv[2][r] - m_r);
                float p11 = __builtin_amdgcn_exp2f(xv[3][r] - m_r);
                rs += (p00 + p01) + (p10 + p11);
                pb0[r] = (bf16_t)p00; pb0[4 + r] = (bf16_t)p01;
                pb1[r] = (bf16_t)p10; pb1[4 + r] = (bf16_t)p11;
            }
            rs += __shfl_xor(rs, 16);
            rs += __shfl_xor(rs, 32);
            l_r += rs;
            __builtin_amdgcn_s_setprio(1);
#pragma unroll
            for (int dd = 0; dd < 8; ++dd) {
                const int dr = dd * 16 + l16;
                bf16x8 va0 = *(const bf16x8*)&Vt[dr * 64 + vc0];
                bf16x8 va1 = *(const bf16x8*)&Vt[dr * 64 + vc1];
                o[dd] = mfma16(va1, pb1, mfma16(va0, pb0, o[dd]));
            }
            __builtin_amdgcn_s_setprio(0);
        }
    }
    if (!split) {
        float inv_l = 1.0f / l_r;
#pragma unroll
        for (int dd = 0; dd < 8; ++dd) {
            bf16x4v ov;
#pragma unroll
            for (int r = 0; r < 4; ++r) ov[r] = (bf16_t)(o[dd][r] * inv_l);
            *(bf16x4v*)&o_out[(size_t)rowq * HIDDEN + h * HDIM + dd * 16 + quad * 4] = ov;
        }
    } else {
        // unnormalized f32 partials; rows 1024..2047; parity = kbase
        const int prow = (h * 1024 + (rowq - 1024)) * 2 + kbase;
        float* op = opart + (size_t)prow * 128;
#pragma unroll
        for (int dd = 0; dd < 8; ++dd)
            *(f32x4*)&op[dd * 16 + quad * 4] = o[dd];
        if (quad == 0) {
            mlpart[prow * 2]     = m_r;
            mlpart[prow * 2 + 1] = l_r;
        }
    }
}

// ---------------- combine the two kv-parity partials for q rows 1024..2047 ----------------
__global__ void combine_kernel(const float* __restrict__ opart, const float* __restrict__ mlpart,
                               bf16_t* __restrict__ o_out) {
    int t = blockIdx.x * 256 + threadIdx.x;   // 28*1024*32 = 917504
    int d4 = t & 31;
    int row = (t >> 5) & 1023;
    int head = t >> 15;
    int base = (head * 1024 + row) * 2;
    float m0 = mlpart[base * 2],     l0 = mlpart[base * 2 + 1];
    float m1 = mlpart[base * 2 + 2], l1 = mlpart[base * 2 + 3];
    float m = fmaxf(m0, m1);
    float a0 = __builtin_amdgcn_exp2f(m0 - m);
    float a1 = __builtin_amdgcn_exp2f(m1 - m);
    float inv = 1.0f / (l0 * a0 + l1 * a1);
    f32x4 o0 = *(const f32x4*)&opart[(size_t)base * 128 + d4 * 4];
    f32x4 o1 = *(const f32x4*)&opart[(size_t)(base + 1) * 128 + d4 * 4];
    bf16x4v ov;
#pragma unroll
    for (int c = 0; c < 4; ++c) ov[c] = (bf16_t)((o0[c] * a0 + o1[c] * a1) * inv);
    *(bf16x4v*)&o_out[(size_t)(1024 + row) * HIDDEN + head * HDIM + d4 * 4] = ov;
}

extern "C" void kernel_launch(void* const* d_in, const int* in_sizes, int n_in,
                              void* d_out, int out_size, void* d_ws, size_t ws_size,
                              hipStream_t stream) {
    const float* hs   = (const float*)d_in[0];
    const float* cosb = (const float*)d_in[1];
    const float* sinb = (const float*)d_in[2];
    const float* Wq   = (const float*)d_in[3];
    const float* bq   = (const float*)d_in[4];
    const float* Wk   = (const float*)d_in[5];
    const float* bk   = (const float*)d_in[6];
    const float* Wv   = (const float*)d_in[7];
    const float* bv   = (const float*)d_in[8];
    const float* Wo   = (const float*)d_in[9];
    float* out = (float*)d_out;

    char* p = (char*)d_ws;
    bf16_t* hsb   = (bf16_t*)p; p += (size_t)SEQ * HIDDEN * 2;        // also reused as attn out
    bf16_t* Wqkvb = (bf16_t*)p; p += (size_t)QKV_LD * HIDDEN * 2;
    bf16_t* Wob   = (bf16_t*)p; p += (size_t)HIDDEN * HIDDEN * 2;
    bf16_t* qkvb  = (bf16_t*)p; p += (size_t)SEQ * QKV_LD * 2;
    float*  bcat  = (float*)p;  p += (size_t)QKV_LD * 4;

    // attn partials overlay the Wqkvb region (dead after gemm1):
    // opart: 28*1024*2*128 f32 = 29.36 MB, mlpart: 28*1024*2*2 f32 = 0.46 MB  (< 33.03 MB)
    float* opart  = (float*)Wqkvb;
    float* mlpart = opart + (size_t)NHEADS * 1024 * 2 * 128;

    const int total_f4 = HS_F4 + WQ_F4 + WK_F4 + WV_F4 + WO_F4 + B_F4;
    cvt_all_kernel<<<(total_f4 + 255) / 256, 256, 0, stream>>>(
        hs, Wq, Wk, Wv, Wo, bq, bk, bv, hsb, Wqkvb, Wob, bcat);

    gemm_bt<true><<<dim3(QKV_LD / 128, SEQ / 128), 256, 0, stream>>>(
        hsb, Wqkvb, bcat, qkvb, SEQ, QKV_LD, HIDDEN);

    rope_kernel<<<(SEQ * 32 * 64) / 256, 256, 0, stream>>>(qkvb, cosb, sinb);

    attn_kernel<<<dim3(24, NHEADS), 512, 0, stream>>>(qkvb, hsb, opart, mlpart);
    combine_kernel<<<NHEADS * 1024 * 32 / 256, 256, 0, stream>>>(opart, mlpart, hsb);

    gemm_bt<false><<<dim3(HIDDEN / 128, SEQ / 128), 256, 0, stream>>>(
        hsb, Wob, nullptr, out, SEQ, HIDDEN, HIDDEN);
}